// Round 8
// baseline (266.629 us; speedup 1.0000x reference)
//
#include <hip/hip_runtime.h>

typedef short bf16x8 __attribute__((ext_vector_type(8)));
typedef float f32x4 __attribute__((ext_vector_type(4)));
typedef unsigned short u16;

#define MFMA16x16x32(a, b, c) __builtin_amdgcn_mfma_f32_16x16x32_bf16((a), (b), (c), 0, 0, 0)

// Problem constants
#define BATCH 4
#define SEQ 2048
#define DMODEL 1024
#define NHEADS 16
#define DHEAD 64
#define MROWS (BATCH * SEQ)  // 8192

// Q projection pre-scale: 1/sqrt(64) * log2(e)  (softmax in base-2 domain)
#define QSCALE 0.18033688011112443f

// native 2^x (single v_exp_f32)
#if defined(__has_builtin)
#if __has_builtin(__builtin_amdgcn_exp2f)
#define EXP2(x) __builtin_amdgcn_exp2f(x)
#endif
#endif
#ifndef EXP2
#define EXP2(x) exp2f(x)
#endif

__device__ __forceinline__ u16 f2bf(float f) {
  unsigned u = __builtin_bit_cast(unsigned, f);
  u += 0x7fffu + ((u >> 16) & 1u);  // RNE
  return (u16)(u >> 16);
}

// async global->LDS, 16B per lane; lane i lands at ldsbase + i*16 (m97/m104 semantics).
__device__ __forceinline__ void gl_lds16(const u16* g, u16* l) {
  __builtin_amdgcn_global_load_lds((__attribute__((address_space(1))) void*)g,
                                   (__attribute__((address_space(3))) void*)l, 16, 0, 0);
}

// ---------------- fused fp32 -> bf16 conversion (one dispatch) ----------------
__global__ void cvt_all(const float* __restrict__ x, const float* __restrict__ wq,
                        const float* __restrict__ wk, const float* __restrict__ wv,
                        const float* __restrict__ wo, u16* __restrict__ xb,
                        u16* __restrict__ wqb, u16* __restrict__ wkb, u16* __restrict__ wvb,
                        u16* __restrict__ wob) {
  int blk = blockIdx.x;
  const float* src;
  u16* dst;
  long off;
  if (blk < 8192) {
    src = x; dst = xb;
    off = (long)blk * 256 + threadIdx.x;
  } else {
    int ws = (blk - 8192) >> 10;
    int wb = (blk - 8192) & 1023;
    src = ws == 0 ? wq : ws == 1 ? wk : ws == 2 ? wv : wo;
    dst = ws == 0 ? wqb : ws == 1 ? wkb : ws == 2 ? wvb : wob;
    off = (long)wb * 256 + threadIdx.x;
  }
  float4 v = reinterpret_cast<const float4*>(src)[off];
  ushort4 o;
  o.x = f2bf(v.x); o.y = f2bf(v.y); o.z = f2bf(v.z); o.w = f2bf(v.w);
  reinterpret_cast<ushort4*>(dst)[off] = o;
}

// ---------------- GEMM core v2: 128x128 tile, BK=64, double-buffered async staging ------
// WAR-safe single-barrier pipeline (attn v3.1 protocol):
//   top of iter i: s_waitcnt vmcnt(0) (own tile-i loads landed — issued a full compute
//   phase ago) ; s_barrier (all waves done reading tile i-1) ; then prefetch tile i+1
//   into buffer (i+1)&1 (provably unread) ; then compute tile i.
// XOR-swizzled unpadded LDS (R4-verified conflict-free).
__device__ __forceinline__ void gemm_core(const u16* __restrict__ A, const u16* __restrict__ Bm,
                                          int row0, int bcol0, u16 (*As)[128 * 64],
                                          u16 (*Bs)[128 * 64], f32x4 (*acc)[4], int tid) {
  const int lane = tid & 63, w = tid >> 6;
  const int wr = w >> 1, wc = w & 1;
  const int quad = lane >> 4, l16 = lane & 15;
  const int lr = lane >> 3;                     // 0..7: row within 8-row staging chunk
  const int lcs = ((lane & 7) ^ lr) * 8;        // swizzled global column (u16)
  const int sw = (l16 & 7) * 8;                 // fragment-read swizzle (u16)

  const long abase = (long)(row0 + lr) * 1024 + lcs;
  const long bbase = (long)(bcol0 + lr) * 1024 + lcs;

  auto stage = [&](int k0, int bufi) {
    u16* Ad = As[bufi];
    u16* Bd = Bs[bufi];
#pragma unroll
    for (int i = 0; i < 4; i++) {
      int rb = i * 32 + w * 8;  // wave-uniform LDS row base (multiple of 8)
      gl_lds16(&A[abase + (long)rb * 1024 + k0], &Ad[rb * 64]);
      gl_lds16(&Bm[bbase + (long)rb * 1024 + k0], &Bd[rb * 64]);
    }
  };

  stage(0, 0);

  for (int it = 0; it < 16; it++) {
    // own tile-it loads landed; all waves finished reading tile it-1
    asm volatile("s_waitcnt vmcnt(0) lgkmcnt(0)\n\ts_barrier" ::: "memory");
    if (it + 1 < 16) stage((it + 1) * 64, (it + 1) & 1);  // WAR-safe: past barrier

    const u16* Asr = As[it & 1];
    const u16* Bsr = Bs[it & 1];
#pragma unroll
    for (int ks = 0; ks < 2; ks++) {
      bf16x8 af[4], bfr[4];
#pragma unroll
      for (int i = 0; i < 4; i++)
        af[i] = *reinterpret_cast<const bf16x8*>(
            &Asr[(wr * 64 + i * 16 + l16) * 64 + ((ks * 32 + quad * 8) ^ sw)]);
#pragma unroll
      for (int j = 0; j < 4; j++)
        bfr[j] = *reinterpret_cast<const bf16x8*>(
            &Bsr[(wc * 64 + j * 16 + l16) * 64 + ((ks * 32 + quad * 8) ^ sw)]);
#pragma unroll
      for (int i = 0; i < 4; i++)
#pragma unroll
        for (int j = 0; j < 4; j++)
          acc[i][j] = MFMA16x16x32(af[i], bfr[j], acc[i][j]);
    }
  }
}

// ---------------- fused QKV projection ----------------
// grid (64, 24): bx = row-tile (fastest -> same col-tile spreads over XCDs; same
// row-tile's 24 col-readers share lin%8 -> same XCD L2 -> A fetched once per XCD).
__global__ __launch_bounds__(256) void gemm_qkv(const u16* __restrict__ xb,
                                                const u16* __restrict__ wqb,
                                                const u16* __restrict__ wkb,
                                                const u16* __restrict__ wvb,
                                                u16* __restrict__ qb, u16* __restrict__ kb,
                                                u16* __restrict__ vtb) {
  __shared__ u16 As[2][128 * 64];
  __shared__ u16 Bs[2][128 * 64];
  const int tid = threadIdx.x;
  const int lane = tid & 63, w = tid >> 6;
  const int wr = w >> 1, wc = w & 1;
  const int quad = lane >> 4, l16 = lane & 15;
  const int row0 = blockIdx.x * 128;   // 0..8191
  const int col0 = blockIdx.y * 128;   // 0..3071
  const int widx = col0 >> 10;         // 0=Q 1=K 2=V (block-uniform)
  const int bcol0 = col0 & 1023;
  const u16* Bm = widx == 0 ? wqb : (widx == 1 ? wkb : wvb);

  f32x4 acc[4][4] = {};
  gemm_core(xb, Bm, row0, bcol0, As, Bs, acc, tid);

#pragma unroll
  for (int i = 0; i < 4; i++)
#pragma unroll
    for (int j = 0; j < 4; j++)
#pragma unroll
      for (int r = 0; r < 4; r++) {
        int row = row0 + wr * 64 + i * 16 + quad * 4 + r;   // b*2048 + l
        int col = bcol0 + wc * 64 + j * 16 + l16;           // h*64 + d
        float v = acc[i][j][r];
        int bh = ((row >> 11) << 4) | (col >> 6);
        if (widx == 0) {
          qb[(bh * SEQ + (row & 2047)) * DHEAD + (col & 63)] = f2bf(v * QSCALE);
        } else if (widx == 1) {
          kb[(bh * SEQ + (row & 2047)) * DHEAD + (col & 63)] = f2bf(v);
        } else {
          vtb[(bh * DHEAD + (col & 63)) * SEQ + (row & 2047)] = f2bf(v);
        }
      }
}

// ---------------- output projection: out = attn @ Wo^T (fp32 store) ----------------
__global__ __launch_bounds__(256) void gemm_out(const u16* __restrict__ aob,
                                                const u16* __restrict__ wob,
                                                float* __restrict__ out) {
  __shared__ u16 As[2][128 * 64];
  __shared__ u16 Bs[2][128 * 64];
  const int tid = threadIdx.x;
  const int lane = tid & 63, w = tid >> 6;
  const int wr = w >> 1, wc = w & 1;
  const int quad = lane >> 4, l16 = lane & 15;
  const int row0 = blockIdx.x * 128;
  const int col0 = blockIdx.y * 128;

  f32x4 acc[4][4] = {};
  gemm_core(aob, wob, row0, col0, As, Bs, acc, tid);

#pragma unroll
  for (int i = 0; i < 4; i++)
#pragma unroll
    for (int j = 0; j < 4; j++)
#pragma unroll
      for (int r = 0; r < 4; r++) {
        int row = row0 + wr * 64 + i * 16 + quad * 4 + r;
        int col = col0 + wc * 64 + j * 16 + l16;
        out[(long)row * DMODEL + col] = acc[i][j][r];
      }
}

// ---------------- Flash attention (causal), v4: max-free base-2 softmax ----------------
__global__ __launch_bounds__(256, 3) void attn_kernel(const u16* __restrict__ Q,
                                                      const u16* __restrict__ Kk,
                                                      const u16* __restrict__ Vt,
                                                      u16* __restrict__ Ao) {
  constexpr int PSTR = 72;
  __shared__ u16 Ksb[2][64 * 64];   // unpadded, XOR-swizzled
  __shared__ u16 Vsb[2][64 * 64];
  __shared__ u16 Plds[4][32 * PSTR];
  const int tid = threadIdx.x;
  const int lane = tid & 63;
  const int w = tid >> 6;
  const int quad = lane >> 4, l16 = lane & 15;
  const int bh = blockIdx.x & 63;
  const int qt = 15 - (blockIdx.x >> 6);  // LPT: heaviest q-tiles first
  const int b = bh >> 4, h = bh & 15;
  const u16* Qh = Q + bh * SEQ * DHEAD;
  const u16* Kh = Kk + bh * SEQ * DHEAD;
  const u16* Vh = Vt + bh * DHEAD * SEQ;
  const int q0w = qt * 128 + w * 32;
  const int nkt = 2 * qt + 2;  // block-uniform

  const int lr = lane >> 3;                  // staging row within 8-row group
  const int swcol = ((lane & 7) ^ lr) * 8;   // swizzled global column (u16)
  const int sw = (l16 & 7) * 8;              // fragment-read swizzle (u16)

  // all-ones bf16 B-fragment for MFMA row-sum (1.0bf16 = 0x3F80)
  bf16x8 onesf;
#pragma unroll
  for (int i = 0; i < 8; i++) onesf[i] = (short)0x3F80;

  // Q fragments (A layout: m=l16, k=quad*8+j), resident
  bf16x8 qf[2][2];
#pragma unroll
  for (int rt = 0; rt < 2; rt++)
#pragma unroll
    for (int ks = 0; ks < 2; ks++)
      qf[rt][ks] = *reinterpret_cast<const bf16x8*>(
          &Qh[(q0w + rt * 16 + l16) * DHEAD + ks * 32 + quad * 8]);

  f32x4 o[2][4] = {};
  f32x4 lacc[2] = {};  // row-sums of P, C-layout

  auto stage = [&](int kb, int bufi) {
    u16* Kd = Ksb[bufi];
    u16* Vd = Vsb[bufi];
#pragma unroll
    for (int i = 0; i < 2; i++) {
      int r = w * 16 + i * 8;  // wave-uniform row base
      gl_lds16(&Kh[(long)(kb + r + lr) * DHEAD + swcol], &Kd[r * 64]);
      gl_lds16(&Vh[(long)(r + lr) * SEQ + kb + swcol], &Vd[r * 64]);
    }
  };

  stage(0, 0);

  for (int kt = 0; kt < nkt; kt++) {
    const int kbase = kt * 64;
    asm volatile("s_waitcnt vmcnt(0) lgkmcnt(0)\n\ts_barrier" ::: "memory");
    if (kt + 1 < nkt) stage(kbase + 64, (kt + 1) & 1);  // WAR-safe: past barrier

    const u16* Ks = Ksb[kt & 1];
    const u16* Vs = Vsb[kt & 1];

    if (kbase <= q0w + 31) {  // wave-uniform causal skip
      // ---- S = Q K^T ----
      f32x4 s[2][4];
#pragma unroll
      for (int nt = 0; nt < 4; nt++) {
        bf16x8 kf0 = *reinterpret_cast<const bf16x8*>(
            &Ks[(nt * 16 + l16) * 64 + ((quad * 8) ^ sw)]);
        bf16x8 kf1 = *reinterpret_cast<const bf16x8*>(
            &Ks[(nt * 16 + l16) * 64 + ((32 + quad * 8) ^ sw)]);
#pragma unroll
        for (int rt = 0; rt < 2; rt++) {
          f32x4 z = {0.f, 0.f, 0.f, 0.f};
          z = MFMA16x16x32(qf[rt][0], kf0, z);
          s[rt][nt] = MFMA16x16x32(qf[rt][1], kf1, z);
        }
      }
      // ---- causal mask (diagonal tiles only) ----
      if (kbase + 63 > q0w) {
#pragma unroll
        for (int rt = 0; rt < 2; rt++)
#pragma unroll
          for (int nt = 0; nt < 4; nt++)
#pragma unroll
            for (int r = 0; r < 4; r++) {
              int qrow = q0w + rt * 16 + quad * 4 + r;
              int kcol = kbase + nt * 16 + l16;
              if (kcol > qrow) s[rt][nt][r] = -1e30f;
            }
      }
      // ---- max-free softmax numerator: P = exp2(s); truncate-pack to bf16 ----
      u16* Pw = Plds[w];
#pragma unroll
      for (int rt = 0; rt < 2; rt++)
#pragma unroll
        for (int nt = 0; nt < 4; nt++)
#pragma unroll
          for (int r = 0; r < 4; r++) {
            float p = EXP2(s[rt][nt][r]);  // masked -> exp2(-1e30) = +0
            Pw[(rt * 16 + quad * 4 + r) * PSTR + nt * 16 + l16] =
                (u16)(__builtin_bit_cast(unsigned, p) >> 16);  // trunc bf16
          }
      asm volatile("s_waitcnt lgkmcnt(0)" ::: "memory");
      bf16x8 pa[2][2];
#pragma unroll
      for (int rt = 0; rt < 2; rt++)
#pragma unroll
        for (int hh = 0; hh < 2; hh++)
          pa[rt][hh] = *reinterpret_cast<const bf16x8*>(
              &Pw[(rt * 16 + l16) * PSTR + hh * 32 + quad * 8]);
      // ---- O += P V ; l += P @ ones ----
#pragma unroll
      for (int nt2 = 0; nt2 < 4; nt2++) {
        bf16x8 vf0 = *reinterpret_cast<const bf16x8*>(
            &Vs[(nt2 * 16 + l16) * 64 + ((quad * 8) ^ sw)]);
        bf16x8 vf1 = *reinterpret_cast<const bf16x8*>(
            &Vs[(nt2 * 16 + l16) * 64 + ((32 + quad * 8) ^ sw)]);
#pragma unroll
        for (int rt = 0; rt < 2; rt++) {
          o[rt][nt2] = MFMA16x16x32(pa[rt][0], vf0, o[rt][nt2]);
          o[rt][nt2] = MFMA16x16x32(pa[rt][1], vf1, o[rt][nt2]);
        }
      }
#pragma unroll
      for (int rt = 0; rt < 2; rt++) {
        lacc[rt] = MFMA16x16x32(pa[rt][0], onesf, lacc[rt]);
        lacc[rt] = MFMA16x16x32(pa[rt][1], onesf, lacc[rt]);
      }
    }
  }

  // ---- epilogue: O / l -> Ao [B, L, H*dh] bf16 ----
#pragma unroll
  for (int rt = 0; rt < 2; rt++) {
    float rl[4];
#pragma unroll
    for (int r = 0; r < 4; r++) rl[r] = 1.0f / lacc[rt][r];
#pragma unroll
    for (int nt2 = 0; nt2 < 4; nt2++)
#pragma unroll
      for (int r = 0; r < 4; r++) {
        int qrow = q0w + rt * 16 + quad * 4 + r;
        float v = o[rt][nt2][r] * rl[r];
        Ao[(b * SEQ + qrow) * DMODEL + h * DHEAD + nt2 * 16 + l16] = f2bf(v);
      }
  }
}

// ---------------- launch ----------------
extern "C" void kernel_launch(void* const* d_in, const int* in_sizes, int n_in,
                              void* d_out, int out_size, void* d_ws, size_t ws_size,
                              hipStream_t stream) {
  const float* x = (const float*)d_in[0];
  const float* Wq = (const float*)d_in[1];
  const float* Wk = (const float*)d_in[2];
  const float* Wv = (const float*)d_in[3];
  const float* Wo = (const float*)d_in[4];
  float* out = (float*)d_out;

  u16* xb  = (u16*)d_ws;
  u16* wqb = xb  + MROWS * DMODEL;
  u16* wkb = wqb + DMODEL * DMODEL;
  u16* wvb = wkb + DMODEL * DMODEL;
  u16* wob = wvb + DMODEL * DMODEL;
  u16* qb  = wob + DMODEL * DMODEL;  // [B,H,L,dh], pre-scaled by QSCALE
  u16* kb  = qb  + MROWS * DMODEL;
  u16* vtb = kb  + MROWS * DMODEL;   // [B,H,dh,L]
  u16* aob = vtb + MROWS * DMODEL;   // [B,L,D]

  cvt_all<<<12288, 256, 0, stream>>>(x, Wq, Wk, Wv, Wo, xb, wqb, wkb, wvb, wob);

  gemm_qkv<<<dim3(64, 24), 256, 0, stream>>>(xb, wqb, wkb, wvb, qb, kb, vtb);

  attn_kernel<<<BATCH * NHEADS * (SEQ / 128), 256, 0, stream>>>(qb, kb, vtb, aob);

  gemm_out<<<dim3(64, 8), 256, 0, stream>>>(aob, wob, out);
}